// Round 5
// baseline (631.420 us; speedup 1.0000x reference)
//
#include <hip/hip_runtime.h>

#define IN_DIM 4096
#define OUT_DIM 4096
#define N_ROWS 8192
#define RANK 256

typedef __bf16 bf16x8 __attribute__((ext_vector_type(8)));
typedef float f32x4 __attribute__((ext_vector_type(4)));
typedef unsigned short u16;
typedef unsigned short u16x4 __attribute__((ext_vector_type(4)));

__device__ __forceinline__ u16 f2b(float f) {
    unsigned int u = __builtin_bit_cast(unsigned int, f);
    unsigned int r = u + 0x7FFFu + ((u >> 16) & 1u);
    return (u16)(r >> 16);
}

__device__ __forceinline__ void async16(const void* g, const void* l) {
    __builtin_amdgcn_global_load_lds(
        (const __attribute__((address_space(1))) void*)g,
        (__attribute__((address_space(3))) void*)l, 16, 0, 0);
}

// prep: blocks 0..127 build AdT[i][r] = bf16(d[r]*A[r][i]) (i-strips of 32);
// blocks 128..1151 convert B -> bf16 (coalesced f32x4).
__global__ __launch_bounds__(256) void vera_prep(
    const float* __restrict__ A, const float* __restrict__ dvec,
    const float* __restrict__ B, u16* __restrict__ adt, u16* __restrict__ Bb) {
    int b = blockIdx.x;
    int t = threadIdx.x;
    if (b < 128) {
        int i0 = b * 32;
        float dv = dvec[t];
        const float* ap = A + (size_t)t * IN_DIM + i0;
#pragma unroll 8
        for (int j = 0; j < 32; ++j)   // writes: 256 consecutive u16 per j
            adt[(size_t)(i0 + j) * RANK + t] =
                f2b(__builtin_nontemporal_load(ap + j) * dv);
    } else {
        int i = (b - 128) * 256 + t;   // covers OUT_DIM*RANK/4 = 262144
        f32x4 v = __builtin_nontemporal_load((const f32x4*)B + i);
        u16x4 o;
        o.x = f2b(v.x); o.y = f2b(v.y); o.z = f2b(v.z); o.w = f2b(v.w);
        *((u16x4*)Bb + i) = o;
    }
}

// C = Aop · Bop^T, bf16 row-major [rows][K]. 128x128 tile, BK=64 laid out as
// two BK=32 half-tiles [2][128][32] so global_load_lds stays contiguous and
// the LDS bank pattern matches the verified m97 layout. 4 waves (2x2), each
// 4x4 of 16x16x32 MFMA; 32 MFMA per barrier-pair (halves barrier drains).
// Blocks >= GB run a grid-stride fp32->bf16 convert (fused aux work).
// MODE 0: out(u16) = bf16(W + bvec[row]*acc)   MODE 1: out(f32) = acc+bvec[col]
template <int MODE, int K, int NN, int TN, int GB>
__global__ __launch_bounds__(256) void vera_gemm(
    const u16* __restrict__ Aop, const u16* __restrict__ Bop,
    const float* __restrict__ W, const float* __restrict__ bvec,
    void* __restrict__ outv,
    const float* __restrict__ cvt_src, u16* __restrict__ cvt_dst, int cvt_n4) {
    __shared__ __align__(16) __bf16 As[2 * 128 * 32];
    __shared__ __align__(16) __bf16 Bs[2 * 128 * 32];

    const int tid = threadIdx.x;
    const int bid = blockIdx.x;

    if (bid >= GB) {   // fused converter blocks
        const int nb = gridDim.x - GB;
        for (int i = (bid - GB) * 256 + tid; i < cvt_n4; i += nb * 256) {
            f32x4 v = __builtin_nontemporal_load((const f32x4*)cvt_src + i);
            u16x4 o;
            o.x = f2b(v.x); o.y = f2b(v.y); o.z = f2b(v.z); o.w = f2b(v.w);
            *((u16x4*)cvt_dst + i) = o;
        }
        return;
    }

    const int lane = tid & 63;
    const int wavei = __builtin_amdgcn_readfirstlane(tid >> 6);
    const int fr = lane & 15;   // A/B frag row; C col
    const int fq = lane >> 4;   // quad
    const int wm = (wavei >> 1) * 64;
    const int wn = (wavei & 1) * 64;

    // swizzle: groups of 8 M-tiles innermost, then N-tiles
    const int g = bid / (8 * TN);
    const int r = bid - g * (8 * TN);
    const int bm = (g * 8 + (r & 7)) * 128;
    const int bn = (r >> 3) * 128;

    // staging: thread t -> 16B chunk: row = t/4 (+64 for rc=1), k = (t%4)*8
    // (+32 elements for half h=1)
    const int srow = tid >> 2;
    const int sk = (tid & 3) * 8;
    const u16* ga0 = Aop + (size_t)(bm + srow) * K + sk;
    const u16* ga1 = Aop + (size_t)(bm + 64 + srow) * K + sk;
    const u16* gb0 = Bop + (size_t)(bn + srow) * K + sk;
    const u16* gb1 = Bop + (size_t)(bn + 64 + srow) * K + sk;

    char* lAs = (char*)As;
    char* lBs = (char*)Bs;
    const int lo = wavei * 1024;   // wave-uniform base; HW adds lane*16

    f32x4 acc[4][4] = {};

    for (int k0 = 0; k0 < K; k0 += 64) {
        __syncthreads();
        // half h=0 (k0..k0+31), rc=0/1 ; half h=1 (k0+32..k0+63)
        async16(ga0 + k0,      lAs + lo);
        async16(ga1 + k0,      lAs + 4096 + lo);
        async16(ga0 + k0 + 32, lAs + 8192 + lo);
        async16(ga1 + k0 + 32, lAs + 12288 + lo);
        async16(gb0 + k0,      lBs + lo);
        async16(gb1 + k0,      lBs + 4096 + lo);
        async16(gb0 + k0 + 32, lBs + 8192 + lo);
        async16(gb1 + k0 + 32, lBs + 12288 + lo);
        __syncthreads();

#pragma unroll
        for (int ks = 0; ks < 2; ++ks) {
            const __bf16* ap = As + ks * 4096 + (wm + fr) * 32 + fq * 8;
            const __bf16* bp = Bs + ks * 4096 + (wn + fr) * 32 + fq * 8;
            bf16x8 af[4], bfr[4];
#pragma unroll
            for (int i = 0; i < 4; ++i) {
                af[i] = *(const bf16x8*)(ap + i * 16 * 32);
                bfr[i] = *(const bf16x8*)(bp + i * 16 * 32);
            }
#pragma unroll
            for (int mi = 0; mi < 4; ++mi)
#pragma unroll
                for (int ni = 0; ni < 4; ++ni)
                    acc[mi][ni] = __builtin_amdgcn_mfma_f32_16x16x32_bf16(
                        af[mi], bfr[ni], acc[mi][ni], 0, 0, 0);
        }
    }

    // C/D layout (m89-verified): col = lane&15, row = (lane>>4)*4 + reg
#pragma unroll
    for (int ni = 0; ni < 4; ++ni) {
        const int col = bn + wn + ni * 16 + fr;
        float bcol = (MODE == 1) ? bvec[col] : 0.f;
#pragma unroll
        for (int mi = 0; mi < 4; ++mi) {
            const int row0 = bm + wm + mi * 16 + fq * 4;
#pragma unroll
            for (int v = 0; v < 4; ++v) {
                const int row = row0 + v;
                float a = acc[mi][ni][v];
                if (MODE == 0) {
                    float wv = __builtin_nontemporal_load(&W[(size_t)row * NN + col]);
                    ((u16*)outv)[(size_t)row * NN + col] = f2b(wv + bvec[row] * a);
                } else {
                    __builtin_nontemporal_store(a + bcol,
                        &((float*)outv)[(size_t)row * NN + col]);
                }
            }
        }
    }
}

extern "C" void kernel_launch(void* const* d_in, const int* in_sizes, int n_in,
                              void* d_out, int out_size, void* d_ws, size_t ws_size,
                              hipStream_t stream) {
    (void)in_sizes; (void)n_in; (void)out_size; (void)ws_size;
    const float* x    = (const float*)d_in[0];   // [N, IN]
    const float* W    = (const float*)d_in[1];   // [OUT, IN]
    const float* bias = (const float*)d_in[2];   // [OUT]
    const float* A    = (const float*)d_in[3];   // [RANK, IN]
    const float* B    = (const float*)d_in[4];   // [OUT, RANK]
    const float* bv   = (const float*)d_in[5];   // [OUT]
    const float* dv   = (const float*)d_in[6];   // [RANK]

    char* ws = (char*)d_ws;
    u16* xb  = (u16*)ws;                                          // 64 MiB
    u16* wb  = (u16*)(ws + (size_t)N_ROWS * IN_DIM * 2);          // 32 MiB
    u16* adt = (u16*)(ws + (size_t)N_ROWS * IN_DIM * 2
                         + (size_t)OUT_DIM * IN_DIM * 2);         // 2 MiB
    u16* Bb  = adt + (size_t)IN_DIM * RANK;                       // 2 MiB

    // 1) prep: AdT = (diag(d) A)^T and B -> bf16
    vera_prep<<<dim3(128 + OUT_DIM * RANK / 4 / 256), 256, 0, stream>>>(
        A, dv, B, adt, Bb);
    // 2) W_eff = W + diag(b)·B·AdT^T  (M=OUT,N=IN,K=RANK; 1024 gemm blocks)
    //    + fused x -> bf16 convert (2048 extra blocks)
    vera_gemm<0, RANK, IN_DIM, IN_DIM / 128, 1024>
        <<<dim3(1024 + 2048), 256, 0, stream>>>(
        Bb, adt, W, bv, wb, x, xb, N_ROWS * IN_DIM / 4);
    // 3) out = x·W_eff^T + bias  (M=N_ROWS,N=OUT,K=IN), fp32 nt out
    vera_gemm<1, IN_DIM, OUT_DIM, OUT_DIM / 128, 2048>
        <<<dim3(2048), 256, 0, stream>>>(
        xb, wb, nullptr, bias, d_out, nullptr, nullptr, 0);
}